// Round 12
// baseline (148.794 us; speedup 1.0000x reference)
//
#include <hip/hip_runtime.h>
#include <math.h>

// ---------------- workspace layout (bytes) ----------------
#define O_RPD    (0)                  // row_ptr dst-CSR (~200KB)
#define O_RPS    (256*1024)           // row_ptr src-CSR
#define O_DINV   (512*1024)           // N floats
#define O_SMALL  (768*1024)           // few KB
#define O_Y      (1024*1024)          // N floats
#define O_RELW   (1280*1024)          // N floats
#define O_REL    (1536*1024)          // N floats
#define O_GHD    (1792*1024)          // NB*256 ints [bucket][chunk]
#define O_GHS    (2048*1024)
#define O_GOD    (2304*1024)
#define O_GOS    (2560*1024)
#define O_BSD    (2816*1024)          // NB+1 ints
#define O_BSS    (2944*1024)
#define O_PART   (3072*1024)          // 1024*132*4 = 540KB
#define O_XS     (3712*1024)          // N float4 = 800KB
#define O_G1     (4608*1024)          // N float4 = 800KB
#define O_SRTD   (5632*1024)          // E uints = 3.2MB
#define O_SRTS   (9216*1024)          // E uints = 3.2MB
#define O_COLD   (12544*1024)         // E ints = 3.2MB
#define O_COLS   (16128*1024)         // E ints = 3.2MB
// small[]: [0..127] w2qk  [128] bias  [264..391] newT

#define NCHUNK 256
#define ZBLOCKS 1024

static __device__ __forceinline__ int blockExclScan256(int v, volatile int* lds, int t) {
    int lane = t & 63, wid = t >> 6;
    int incl = v;
#pragma unroll
    for (int off = 1; off < 64; off <<= 1) {
        int n = __shfl_up(incl, off);
        if (lane >= off) incl += n;
    }
    if (lane == 63) lds[wid] = incl;
    __syncthreads();
    if (t == 0) {
        int s = 0;
#pragma unroll
        for (int i = 0; i < 4; ++i) { int x = lds[i]; lds[i] = s; s += x; }
    }
    __syncthreads();
    return lds[wid] + incl - v;
}

// ---------------- A1: per-chunk bucket histograms (both orientations); spare block: tiny1 ----
__global__ void k_hist(const int* __restrict__ eidx, int* __restrict__ ghD,
                       int* __restrict__ ghS,
                       const float* __restrict__ trainOT, const float* __restrict__ Wq,
                       const float* __restrict__ bq, const float* __restrict__ Wk,
                       const float* __restrict__ bk, const float* __restrict__ W2,
                       const float* __restrict__ b2, float* __restrict__ small,
                       int E, int CS, int NB) {
    int b = blockIdx.x, t = threadIdx.x;
    if (b == NCHUNK) {
        if (blockIdx.y) return;
        // ---- tiny1: w2qk & bias ----
        __shared__ float kv[64];
        __shared__ float wqk[128];
        __shared__ float fred[256];
        if (t < 64) {
            float acc = bk[t];
            for (int j = 0; j < 128; ++j) acc += trainOT[j] * Wk[j * 64 + t];
            kv[t] = acc;
        }
        __syncthreads();
        if (t < 128) {
            float aq = 0.f;
            for (int c2 = 0; c2 < 64; ++c2) aq += Wq[t * 64 + c2] * kv[c2];
            wqk[t] = aq;
        }
        fred[t] = (t < 64) ? bq[t] * kv[t] : 0.f;
        __syncthreads();
        for (int off = 128; off >= 1; off >>= 1) { if (t < off) fred[t] += fred[t + off]; __syncthreads(); }
        float bqs = fred[0];
        __syncthreads();
        if (t < 128) {
            float a2 = 0.f;
            for (int j = 0; j < 128; ++j) a2 += W2[t * 128 + j] * wqk[j];
            small[t] = a2;
        }
        fred[t] = (t < 128) ? b2[t] * wqk[t] : 0.f;
        __syncthreads();
        for (int off = 128; off >= 1; off >>= 1) { if (t < off) fred[t] += fred[t + off]; __syncthreads(); }
        if (t == 0) small[128] = bqs + fred[0];
        return;
    }
    __shared__ int lh[256];
    const int* arr = blockIdx.y ? eidx : (eidx + E);      // y=0: dst, y=1: src
    int* gh = blockIdx.y ? ghS : ghD;
    lh[t] = 0; __syncthreads();
    int s = b * CS, e = min(E, s + CS);
    for (int i = s + t; i < e; i += 256) atomicAdd(&lh[arr[i] >> 8], 1);
    __syncthreads();
    if (t < NB) gh[t * NCHUNK + b] = lh[t];               // transposed: [bucket][chunk]
}

// ---------------- A2: bucket totals + scans (both orientations) ----------------
__global__ void k_bstart(const int* __restrict__ ghD, const int* __restrict__ ghS,
                         int* __restrict__ bsD, int* __restrict__ bsS, int NB) {
    __shared__ int lds1[4];
    __shared__ int lds2[4];
    int t = threadIdx.x;   // 256
    int vD = 0, vS = 0;
    if (t < NB) {
        const int* rD = ghD + t * NCHUNK;
        const int* rS = ghS + t * NCHUNK;
        for (int b = 0; b < NCHUNK; ++b) { vD += rD[b]; vS += rS[b]; }
    }
    int exD = blockExclScan256(vD, lds1, t);
    if (t <= NB) bsD[t] = exD;
    __syncthreads();
    int exS = blockExclScan256(vS, lds2, t);
    if (t <= NB) bsS[t] = exS;
}

// ---------------- A3: per-bucket chunk offsets (grid NB x 2) ----------------
__global__ void k_goff(const int* __restrict__ ghD, const int* __restrict__ ghS,
                       const int* __restrict__ bsD, const int* __restrict__ bsS,
                       int* __restrict__ goD, int* __restrict__ goS, int NB) {
    __shared__ int lds1[4];
    int nb = blockIdx.x, t = threadIdx.x;
    const int* gh = blockIdx.y ? ghS : ghD;
    const int* bs = blockIdx.y ? bsS : bsD;
    int* go = blockIdx.y ? goS : goD;
    int base = bs[nb];
    int g = gh[nb * NCHUNK + t];
    int gx = blockExclScan256(g, lds1, t);
    go[nb * NCHUNK + t] = base + gx;
}

// ---------------- A4: scatter edges into bucket-sorted runs (grid NCHUNK x 2) ----------------
__global__ void k_scatter(const int* __restrict__ eidx, const int* __restrict__ goD,
                          const int* __restrict__ goS, unsigned int* __restrict__ srtD,
                          unsigned int* __restrict__ srtS, int E, int CS, int NB) {
    __shared__ int lcur[256];
    int b = blockIdx.x, t = threadIdx.x;
    const int* key = blockIdx.y ? eidx : (eidx + E);      // y=0: key=dst,val=src; y=1: key=src,val=dst
    const int* val = blockIdx.y ? (eidx + E) : eidx;
    const int* go  = blockIdx.y ? goS : goD;
    unsigned int* srt = blockIdx.y ? srtS : srtD;
    if (t < NB) lcur[t] = go[t * NCHUNK + b];
    __syncthreads();
    int s = b * CS, e = min(E, s + CS);
    for (int i = s + t; i < e; i += 256) {
        int k = key[i];
        int pos = atomicAdd(&lcur[k >> 8], 1);
        srt[pos] = ((unsigned int)(k & 255) << 16) | (unsigned int)val[i];   // N <= 65536
    }
}

// ---------------- B: per-bucket degree + row_ptr + CSR fill; fwd also dinv/xs4 ----------
__global__ void k_build(const unsigned int* __restrict__ srtD, const unsigned int* __restrict__ srtS,
                        const int* __restrict__ bsD, const int* __restrict__ bsS,
                        int* __restrict__ rpD, int* __restrict__ rpS,
                        int* __restrict__ colD, int* __restrict__ colS,
                        float* __restrict__ dinv, const float* __restrict__ x,
                        float4* __restrict__ xs4, int N, int NB) {
    __shared__ int lcnt[256];
    __shared__ int lpos[256];
    __shared__ int lds1[4];
    int nb = blockIdx.x, t = threadIdx.x;
    bool rev = blockIdx.y != 0;
    const unsigned int* srt = rev ? srtS : srtD;
    const int* bst = rev ? bsS : bsD;
    int* rp  = rev ? rpS : rpD;
    int* col = rev ? colS : colD;
    lcnt[t] = 0; __syncthreads();
    int s = bst[nb], e = bst[nb + 1];
    for (int i = s + t; i < e; i += 256) atomicAdd(&lcnt[srt[i] >> 16], 1);
    __syncthreads();
    int c = lcnt[t];
    int cx = blockExclScan256(c, lds1, t);
    int rpv = s + cx;
    int node = (nb << 8) + t;
    rp[node] = rpv;
    lpos[t] = rpv;
    if (!rev && node < N) {
        float d = rsqrtf((float)(c + 1));   // +1 self-loop
        dinv[node] = d;
        float4 v;
        v.x = x[node * 3] * d; v.y = x[node * 3 + 1] * d; v.z = x[node * 3 + 2] * d; v.w = 0.f;
        xs4[node] = v;
    }
    __syncthreads();
    for (int i = s + t; i < e; i += 256) {
        unsigned int v = srt[i];
        int p = atomicAdd(&lpos[v >> 16], 1);
        col[p] = (int)(v & 0xffffu);
    }
}

// ---------------- layer 1: 16 lanes/node; store g1=(agg,di) + y ----------------
__global__ void k_y(const float4* __restrict__ xs4, const int* __restrict__ rpD,
                    const int* __restrict__ colD, const float* __restrict__ dinv,
                    const float* __restrict__ W1, const float* __restrict__ b1,
                    const float* __restrict__ small, float4* __restrict__ g1,
                    float* __restrict__ y, int N) {
    int t = threadIdx.x;
    int sub = t & 15;
    int node = blockIdx.x * 16 + (t >> 4);
    if (node >= N) return;
    float di = dinv[node];
    int s = rpD[node], e = rpD[node + 1];
    float a0 = 0.f, a1 = 0.f, a2 = 0.f;
    for (int j = s + sub; j < e; j += 16) {
        float4 xv = xs4[colD[j]];
        a0 += xv.x; a1 += xv.y; a2 += xv.z;
    }
    if (sub == 0) { float4 xv = xs4[node]; a0 += xv.x; a1 += xv.y; a2 += xv.z; }
#pragma unroll
    for (int off = 1; off < 16; off <<= 1) {
        a0 += __shfl_xor(a0, off);
        a1 += __shfl_xor(a1, off);
        a2 += __shfl_xor(a2, off);
    }
    a0 *= di; a1 *= di; a2 *= di;
    float yl = 0.f;
#pragma unroll
    for (int m = 0; m < 8; ++m) {
        int c = sub * 8 + m;
        float h = fmaxf(a0 * W1[c] + a1 * W1[128 + c] + a2 * W1[256 + c] + b1[c], 0.f);
        yl += h * small[c];
    }
#pragma unroll
    for (int off = 1; off < 16; off <<= 1) yl += __shfl_xor(yl, off);
    if (sub == 0) {
        y[node] = yl * di;
        float4 gv; gv.x = a0; gv.y = a1; gv.z = a2; gv.w = di;
        g1[node] = gv;
    }
}

// ---------------- dv/rel: scalar aggregation of y over dst-CSR ----------------
__global__ void k_dv(const float* __restrict__ y, const int* __restrict__ rpD,
                     const int* __restrict__ colD, const float* __restrict__ dinv,
                     const float* __restrict__ small, float* __restrict__ relw,
                     float* __restrict__ rel, int N) {
    int t = threadIdx.x;
    int sub = t & 15;
    int node = blockIdx.x * 16 + (t >> 4);
    if (node >= N) return;
    float di = dinv[node];
    int s = rpD[node], e = rpD[node + 1];
    float acc = (sub == 0) ? y[node] : 0.f;
    for (int j = s + sub; j < e; j += 16) acc += y[colD[j]];
#pragma unroll
    for (int off = 1; off < 16; off <<= 1) acc += __shfl_xor(acc, off);
    float z = (acc * di + small[128]) * 0.125f;     // / sqrt(64)
    float r = 1.f / (1.f + __expf(-z));
    if (sub == 0) { rel[node] = r; relw[node] = r * di; }
}

// ---------------- z + S: z[u]=relw[u]+sum_{u->n}relw[n]; S += z[u]*dinv[u]*h1[u] ----------
__global__ void k_z(const float4* __restrict__ g1, const int* __restrict__ rpS,
                    const int* __restrict__ colS, const float* __restrict__ relw,
                    const float* __restrict__ rel, const float* __restrict__ W1,
                    const float* __restrict__ b1, float* __restrict__ part, int N) {
    __shared__ float W1s[384];
    __shared__ float b1s[128];
    __shared__ float sS[4][132];
    int t = threadIdx.x, lane = t & 63, wid = t >> 6;
    int sub = lane & 15;
    if (t < 128) { W1s[t] = W1[t]; W1s[128 + t] = W1[128 + t]; W1s[256 + t] = W1[256 + t];
                   b1s[t] = b1[t]; }
    __syncthreads();
    float acc[8];
#pragma unroll
    for (int m = 0; m < 8; ++m) acc[m] = 0.f;
    float Racc = 0.f;
    for (int node = blockIdx.x * 16 + (t >> 4); node < N; node += ZBLOCKS * 16) {
        int s = rpS[node], e = rpS[node + 1];
        float w = (sub == 0) ? relw[node] : 0.f;
        for (int j = s + sub; j < e; j += 16) w += relw[colS[j]];
#pragma unroll
        for (int off = 1; off < 16; off <<= 1) w += __shfl_xor(w, off);
        float4 gv = g1[node];
        float zw = w * gv.w;                       // z * dinv
#pragma unroll
        for (int m = 0; m < 8; ++m) {
            int c = sub * 8 + m;
            float h = fmaxf(gv.x * W1s[c] + gv.y * W1s[128 + c] + gv.z * W1s[256 + c] + b1s[c], 0.f);
            acc[m] += zw * h;
        }
        if (sub == 0) Racc += rel[node];
    }
#pragma unroll
    for (int m = 0; m < 8; ++m) {
        acc[m] += __shfl_xor(acc[m], 16);
        acc[m] += __shfl_xor(acc[m], 32);
    }
    Racc += __shfl_xor(Racc, 16);
    Racc += __shfl_xor(Racc, 32);
    if (lane < 16) {
#pragma unroll
        for (int m = 0; m < 8; ++m) sS[wid][sub * 8 + m] = acc[m];
    }
    if (lane == 0) sS[wid][128] = Racc;
    __syncthreads();
    if (t < 129) part[blockIdx.x * 132 + t] = sS[0][t] + sS[1][t] + sS[2][t] + sS[3][t];
}

// ---------------- tail: reduce part (1024 rows) -> S,R; newT = trainOT+(S@W2+R*b2)@Wv+R*bv -
__global__ void k_tailred(const float* __restrict__ trainOT, const float* __restrict__ W2,
                          const float* __restrict__ b2, const float* __restrict__ Wv,
                          const float* __restrict__ bv, const float* __restrict__ part,
                          float* __restrict__ small, float* __restrict__ out_tail) {
    __shared__ float acc8[1024];
    __shared__ float Ss[129];
    __shared__ float t1[128];
    __shared__ float r8[8];
    int t = threadIdx.x;            // 1024
    int c = t >> 3, sl = t & 7;     // 128 cols x 8 slices
    float s = 0.f;
    for (int b = sl; b < ZBLOCKS; b += 8) s += part[b * 132 + c];
    acc8[t] = s;
    if (t < 8) {
        float r = 0.f;
        for (int b = t; b < ZBLOCKS; b += 8) r += part[b * 132 + 128];
        r8[t] = r;
    }
    __syncthreads();
    if (t < 128) {
        float v = 0.f;
#pragma unroll
        for (int k = 0; k < 8; ++k) v += acc8[t * 8 + k];
        Ss[t] = v;
    }
    if (t == 0) Ss[128] = r8[0] + r8[1] + r8[2] + r8[3] + r8[4] + r8[5] + r8[6] + r8[7];
    __syncthreads();
    float R = Ss[128];
    int o = t & 127, s2 = t >> 7;   // 8 K-slices of 16
    float a1 = 0.f;
#pragma unroll
    for (int j = s2 * 16; j < s2 * 16 + 16; ++j) a1 += Ss[j] * W2[j * 128 + o];
    acc8[t] = a1; __syncthreads();
    if (t < 128) {
        float v = R * b2[t];
#pragma unroll
        for (int k = 0; k < 8; ++k) v += acc8[t + 128 * k];
        t1[t] = v;
    }
    __syncthreads();
    float a2 = 0.f;
#pragma unroll
    for (int j = s2 * 16; j < s2 * 16 + 16; ++j) a2 += t1[j] * Wv[j * 128 + o];
    acc8[t] = a2; __syncthreads();
    if (t < 128) {
        float v = R * bv[t];
#pragma unroll
        for (int k = 0; k < 8; ++k) v += acc8[t + 128 * k];
        float nt = trainOT[t] + v;
        small[264 + t] = nt;
        out_tail[t] = nt;
    }
}

// ---------------- speak: out[j] = newT @ Ws[:,j] + bs[j], 4 K-slices, LDS reduce ----------
__global__ void k_speak(const float* __restrict__ Ws, const float* __restrict__ bs,
                        const float* __restrict__ small, float* __restrict__ out, int out_n) {
    __shared__ float nt[128];
    __shared__ float s0[256], s1[256];
    int t = threadIdx.x;
    if (t < 128) nt[t] = small[264 + t];
    __syncthreads();
    int jj = (t & 63) * 2, sl = t >> 6;       // 4 K-slices of 32
    int j = blockIdx.x * 128 + jj;
    float a0 = 0.f, a1 = 0.f;
    if (j < out_n) {
        const float* w = Ws + (size_t)(sl * 32) * out_n + j;
        for (int k = 0; k < 32; ++k) {
            float cv = nt[sl * 32 + k];
            float2 r = *reinterpret_cast<const float2*>(w + (size_t)k * out_n);
            a0 += cv * r.x; a1 += cv * r.y;
        }
    }
    s0[t] = a0; s1[t] = a1; __syncthreads();
    if (t < 64 && j < out_n) {
        out[j]     = s0[t] + s0[t + 64] + s0[t + 128] + s0[t + 192] + bs[j];
        out[j + 1] = s1[t] + s1[t + 64] + s1[t + 128] + s1[t + 192] + bs[j + 1];
    }
}

extern "C" void kernel_launch(void* const* d_in, const int* in_sizes, int n_in,
                              void* d_out, int out_size, void* d_ws, size_t ws_size,
                              hipStream_t stream) {
    const float* features = (const float*)d_in[0];
    const int*   eidx     = (const int*)d_in[1];
    const float* trainOT  = (const float*)d_in[2];
    const float* W1 = (const float*)d_in[3];
    const float* b1 = (const float*)d_in[4];
    const float* W2 = (const float*)d_in[5];
    const float* b2 = (const float*)d_in[6];
    const float* Wq = (const float*)d_in[7];
    const float* bq = (const float*)d_in[8];
    const float* Wk = (const float*)d_in[9];
    const float* bk = (const float*)d_in[10];
    const float* Wv = (const float*)d_in[11];
    const float* bv = (const float*)d_in[12];
    const float* Ws = (const float*)d_in[13];
    const float* bs = (const float*)d_in[14];

    int N = in_sizes[0] / 3;
    int E = in_sizes[1] / 2;
    int NB = (N + 255) >> 8;
    int CS = (E + NCHUNK - 1) / NCHUNK;

    char* ws = (char*)d_ws;
    int*   rpD   = (int*)(ws + O_RPD);
    int*   rpS   = (int*)(ws + O_RPS);
    float* dinv  = (float*)(ws + O_DINV);
    float* small = (float*)(ws + O_SMALL);
    float* y     = (float*)(ws + O_Y);
    float* relw  = (float*)(ws + O_RELW);
    float* rel   = (float*)(ws + O_REL);
    int*   ghD   = (int*)(ws + O_GHD);
    int*   ghS   = (int*)(ws + O_GHS);
    int*   goD   = (int*)(ws + O_GOD);
    int*   goS   = (int*)(ws + O_GOS);
    int*   bsD   = (int*)(ws + O_BSD);
    int*   bsS   = (int*)(ws + O_BSS);
    float* part  = (float*)(ws + O_PART);
    float4* xs4  = (float4*)(ws + O_XS);
    float4* g1   = (float4*)(ws + O_G1);
    unsigned int* srtD = (unsigned int*)(ws + O_SRTD);
    unsigned int* srtS = (unsigned int*)(ws + O_SRTS);
    int*   colD  = (int*)(ws + O_COLD);
    int*   colS  = (int*)(ws + O_COLS);
    float* out   = (float*)d_out;
    int out_n = out_size - 128;

    k_hist<<<dim3(NCHUNK + 1, 2), 256, 0, stream>>>(eidx, ghD, ghS,
                                                    trainOT, Wq, bq, Wk, bk, W2, b2, small,
                                                    E, CS, NB);
    k_bstart<<<1, 256, 0, stream>>>(ghD, ghS, bsD, bsS, NB);
    k_goff<<<dim3(NB, 2), 256, 0, stream>>>(ghD, ghS, bsD, bsS, goD, goS, NB);
    k_scatter<<<dim3(NCHUNK, 2), 256, 0, stream>>>(eidx, goD, goS, srtD, srtS, E, CS, NB);
    k_build<<<dim3(NB, 2), 256, 0, stream>>>(srtD, srtS, bsD, bsS, rpD, rpS, colD, colS,
                                             dinv, features, xs4, N, NB);
    k_y<<<(N + 15) / 16, 256, 0, stream>>>(xs4, rpD, colD, dinv, W1, b1, small, g1, y, N);
    k_dv<<<(N + 15) / 16, 256, 0, stream>>>(y, rpD, colD, dinv, small, relw, rel, N);
    k_z<<<ZBLOCKS, 256, 0, stream>>>(g1, rpS, colS, relw, rel, W1, b1, part, N);
    k_tailred<<<1, 1024, 0, stream>>>(trainOT, W2, b2, Wv, bv, part, small, out + out_n);
    k_speak<<<(out_n + 127) / 128, 256, 0, stream>>>(Ws, bs, small, out, out_n);
}

// Round 13
// 104.119 us; speedup vs baseline: 1.4291x; 1.4291x over previous
//
#include <hip/hip_runtime.h>
#include <math.h>

// ---------------- workspace layout (bytes) ----------------
#define O_RPD    (0)                  // row_ptr dst-CSR (~200KB)
#define O_RPS    (256*1024)           // row_ptr src-CSR
#define O_DINV   (512*1024)           // N floats
#define O_SMALL  (768*1024)           // few KB
#define O_Y      (1024*1024)          // N floats
#define O_RELW   (1280*1024)          // N floats
#define O_REL    (1536*1024)          // N floats
#define O_GHD    (1792*1024)          // NB*256 ints [bucket][chunk]
#define O_GHS    (2048*1024)
#define O_GOD    (2304*1024)
#define O_GOS    (2560*1024)
#define O_BSD    (2816*1024)          // NB+1 ints
#define O_BSS    (2944*1024)
#define O_PART   (3072*1024)          // 1024*132*4 = 540KB
#define O_XS     (3712*1024)          // N float4 = 800KB
#define O_G1     (4608*1024)          // N float4 = 800KB
#define O_SRTD   (5632*1024)          // E uints = 3.2MB
#define O_SRTS   (9216*1024)          // E uints = 3.2MB
#define O_COLD   (12544*1024)         // E ints = 3.2MB
#define O_COLS   (16128*1024)         // E ints = 3.2MB
// small[]: [0..127] w2qk  [128] bias  [132..259] S  [260] R  [264..391] newT

#define NCHUNK 256
#define ZBLOCKS 1024

static __device__ __forceinline__ int blockExclScan256(int v, volatile int* lds, int t) {
    int lane = t & 63, wid = t >> 6;
    int incl = v;
#pragma unroll
    for (int off = 1; off < 64; off <<= 1) {
        int n = __shfl_up(incl, off);
        if (lane >= off) incl += n;
    }
    if (lane == 63) lds[wid] = incl;
    __syncthreads();
    if (t == 0) {
        int s = 0;
#pragma unroll
        for (int i = 0; i < 4; ++i) { int x = lds[i]; lds[i] = s; s += x; }
    }
    __syncthreads();
    return lds[wid] + incl - v;
}

// ---------------- A1: per-chunk bucket histograms (both orientations); spare block: tiny1 ----
__global__ void k_hist(const int* __restrict__ eidx, int* __restrict__ ghD,
                       int* __restrict__ ghS,
                       const float* __restrict__ trainOT, const float* __restrict__ Wq,
                       const float* __restrict__ bq, const float* __restrict__ Wk,
                       const float* __restrict__ bk, const float* __restrict__ W2,
                       const float* __restrict__ b2, float* __restrict__ small,
                       int E, int CS, int NB) {
    int b = blockIdx.x, t = threadIdx.x;
    if (b == NCHUNK) {
        if (blockIdx.y) return;
        // ---- tiny1: w2qk & bias ----
        __shared__ float kv[64];
        __shared__ float wqk[128];
        __shared__ float fred[256];
        if (t < 64) {
            float acc = bk[t];
            for (int j = 0; j < 128; ++j) acc += trainOT[j] * Wk[j * 64 + t];
            kv[t] = acc;
        }
        __syncthreads();
        if (t < 128) {
            float aq = 0.f;
            for (int c2 = 0; c2 < 64; ++c2) aq += Wq[t * 64 + c2] * kv[c2];
            wqk[t] = aq;
        }
        fred[t] = (t < 64) ? bq[t] * kv[t] : 0.f;
        __syncthreads();
        for (int off = 128; off >= 1; off >>= 1) { if (t < off) fred[t] += fred[t + off]; __syncthreads(); }
        float bqs = fred[0];
        __syncthreads();
        if (t < 128) {
            float a2 = 0.f;
            for (int j = 0; j < 128; ++j) a2 += W2[t * 128 + j] * wqk[j];
            small[t] = a2;
        }
        fred[t] = (t < 128) ? b2[t] * wqk[t] : 0.f;
        __syncthreads();
        for (int off = 128; off >= 1; off >>= 1) { if (t < off) fred[t] += fred[t + off]; __syncthreads(); }
        if (t == 0) small[128] = bqs + fred[0];
        return;
    }
    __shared__ int lh[256];
    const int* arr = blockIdx.y ? eidx : (eidx + E);      // y=0: dst, y=1: src
    int* gh = blockIdx.y ? ghS : ghD;
    lh[t] = 0; __syncthreads();
    int s = b * CS, e = min(E, s + CS);
    for (int i = s + t; i < e; i += 256) atomicAdd(&lh[arr[i] >> 8], 1);
    __syncthreads();
    if (t < NB) gh[t * NCHUNK + b] = lh[t];               // transposed: [bucket][chunk]
}

// ---------------- A2: bucket totals + scans (both orientations) ----------------
__global__ void k_bstart(const int* __restrict__ ghD, const int* __restrict__ ghS,
                         int* __restrict__ bsD, int* __restrict__ bsS, int NB) {
    __shared__ int lds1[4];
    __shared__ int lds2[4];
    int t = threadIdx.x;   // 256
    int vD = 0, vS = 0;
    if (t < NB) {
        const int* rD = ghD + t * NCHUNK;
        const int* rS = ghS + t * NCHUNK;
        for (int b = 0; b < NCHUNK; ++b) { vD += rD[b]; vS += rS[b]; }
    }
    int exD = blockExclScan256(vD, lds1, t);
    if (t <= NB) bsD[t] = exD;
    __syncthreads();
    int exS = blockExclScan256(vS, lds2, t);
    if (t <= NB) bsS[t] = exS;
}

// ---------------- A3: per-bucket chunk offsets (grid NB x 2) ----------------
__global__ void k_goff(const int* __restrict__ ghD, const int* __restrict__ ghS,
                       const int* __restrict__ bsD, const int* __restrict__ bsS,
                       int* __restrict__ goD, int* __restrict__ goS, int NB) {
    __shared__ int lds1[4];
    int nb = blockIdx.x, t = threadIdx.x;
    const int* gh = blockIdx.y ? ghS : ghD;
    const int* bs = blockIdx.y ? bsS : bsD;
    int* go = blockIdx.y ? goS : goD;
    int base = bs[nb];
    int g = gh[nb * NCHUNK + t];
    int gx = blockExclScan256(g, lds1, t);
    go[nb * NCHUNK + t] = base + gx;
}

// ---------------- A4: scatter edges into bucket-sorted runs (grid NCHUNK x 2) ----------------
__global__ void k_scatter(const int* __restrict__ eidx, const int* __restrict__ goD,
                          const int* __restrict__ goS, unsigned int* __restrict__ srtD,
                          unsigned int* __restrict__ srtS, int E, int CS, int NB) {
    __shared__ int lcur[256];
    int b = blockIdx.x, t = threadIdx.x;
    const int* key = blockIdx.y ? eidx : (eidx + E);      // y=0: key=dst,val=src; y=1: key=src,val=dst
    const int* val = blockIdx.y ? (eidx + E) : eidx;
    const int* go  = blockIdx.y ? goS : goD;
    unsigned int* srt = blockIdx.y ? srtS : srtD;
    if (t < NB) lcur[t] = go[t * NCHUNK + b];
    __syncthreads();
    int s = b * CS, e = min(E, s + CS);
    for (int i = s + t; i < e; i += 256) {
        int k = key[i];
        int pos = atomicAdd(&lcur[k >> 8], 1);
        srt[pos] = ((unsigned int)(k & 255) << 16) | (unsigned int)val[i];   // N <= 65536
    }
}

// ---------------- B: per-bucket degree + row_ptr + CSR fill; fwd also dinv/xs4 ----------
__global__ void k_build(const unsigned int* __restrict__ srtD, const unsigned int* __restrict__ srtS,
                        const int* __restrict__ bsD, const int* __restrict__ bsS,
                        int* __restrict__ rpD, int* __restrict__ rpS,
                        int* __restrict__ colD, int* __restrict__ colS,
                        float* __restrict__ dinv, const float* __restrict__ x,
                        float4* __restrict__ xs4, int N, int NB) {
    __shared__ int lcnt[256];
    __shared__ int lpos[256];
    __shared__ int lds1[4];
    int nb = blockIdx.x, t = threadIdx.x;
    bool rev = blockIdx.y != 0;
    const unsigned int* srt = rev ? srtS : srtD;
    const int* bst = rev ? bsS : bsD;
    int* rp  = rev ? rpS : rpD;
    int* col = rev ? colS : colD;
    lcnt[t] = 0; __syncthreads();
    int s = bst[nb], e = bst[nb + 1];
    for (int i = s + t; i < e; i += 256) atomicAdd(&lcnt[srt[i] >> 16], 1);
    __syncthreads();
    int c = lcnt[t];
    int cx = blockExclScan256(c, lds1, t);
    int rpv = s + cx;
    int node = (nb << 8) + t;
    rp[node] = rpv;
    lpos[t] = rpv;
    if (!rev && node < N) {
        float d = rsqrtf((float)(c + 1));   // +1 self-loop
        dinv[node] = d;
        float4 v;
        v.x = x[node * 3] * d; v.y = x[node * 3 + 1] * d; v.z = x[node * 3 + 2] * d; v.w = 0.f;
        xs4[node] = v;
    }
    __syncthreads();
    for (int i = s + t; i < e; i += 256) {
        unsigned int v = srt[i];
        int p = atomicAdd(&lpos[v >> 16], 1);
        col[p] = (int)(v & 0xffffu);
    }
}

// ---------------- layer 1: 16 lanes/node; store g1=(agg,di) + y ----------------
__global__ void k_y(const float4* __restrict__ xs4, const int* __restrict__ rpD,
                    const int* __restrict__ colD, const float* __restrict__ dinv,
                    const float* __restrict__ W1, const float* __restrict__ b1,
                    const float* __restrict__ small, float4* __restrict__ g1,
                    float* __restrict__ y, int N) {
    int t = threadIdx.x;
    int sub = t & 15;
    int node = blockIdx.x * 16 + (t >> 4);
    if (node >= N) return;
    float di = dinv[node];
    int s = rpD[node], e = rpD[node + 1];
    float a0 = 0.f, a1 = 0.f, a2 = 0.f;
    for (int j = s + sub; j < e; j += 16) {
        float4 xv = xs4[colD[j]];
        a0 += xv.x; a1 += xv.y; a2 += xv.z;
    }
    if (sub == 0) { float4 xv = xs4[node]; a0 += xv.x; a1 += xv.y; a2 += xv.z; }
#pragma unroll
    for (int off = 1; off < 16; off <<= 1) {
        a0 += __shfl_xor(a0, off);
        a1 += __shfl_xor(a1, off);
        a2 += __shfl_xor(a2, off);
    }
    a0 *= di; a1 *= di; a2 *= di;
    float yl = 0.f;
#pragma unroll
    for (int m = 0; m < 8; ++m) {
        int c = sub * 8 + m;
        float h = fmaxf(a0 * W1[c] + a1 * W1[128 + c] + a2 * W1[256 + c] + b1[c], 0.f);
        yl += h * small[c];
    }
#pragma unroll
    for (int off = 1; off < 16; off <<= 1) yl += __shfl_xor(yl, off);
    if (sub == 0) {
        y[node] = yl * di;
        float4 gv; gv.x = a0; gv.y = a1; gv.z = a2; gv.w = di;
        g1[node] = gv;
    }
}

// ---------------- dv/rel: scalar aggregation of y over dst-CSR ----------------
__global__ void k_dv(const float* __restrict__ y, const int* __restrict__ rpD,
                     const int* __restrict__ colD, const float* __restrict__ dinv,
                     const float* __restrict__ small, float* __restrict__ relw,
                     float* __restrict__ rel, int N) {
    int t = threadIdx.x;
    int sub = t & 15;
    int node = blockIdx.x * 16 + (t >> 4);
    if (node >= N) return;
    float di = dinv[node];
    int s = rpD[node], e = rpD[node + 1];
    float acc = (sub == 0) ? y[node] : 0.f;
    for (int j = s + sub; j < e; j += 16) acc += y[colD[j]];
#pragma unroll
    for (int off = 1; off < 16; off <<= 1) acc += __shfl_xor(acc, off);
    float z = (acc * di + small[128]) * 0.125f;     // / sqrt(64)
    float r = 1.f / (1.f + __expf(-z));
    if (sub == 0) { rel[node] = r; relw[node] = r * di; }
}

// ---------------- z + S: z[u]=relw[u]+sum_{u->n}relw[n]; S += z[u]*dinv[u]*h1[u] ----------
__global__ void k_z(const float4* __restrict__ g1, const int* __restrict__ rpS,
                    const int* __restrict__ colS, const float* __restrict__ relw,
                    const float* __restrict__ rel, const float* __restrict__ W1,
                    const float* __restrict__ b1, float* __restrict__ part, int N) {
    __shared__ float W1s[384];
    __shared__ float b1s[128];
    __shared__ float sS[4][132];
    int t = threadIdx.x, lane = t & 63, wid = t >> 6;
    int sub = lane & 15;
    if (t < 128) { W1s[t] = W1[t]; W1s[128 + t] = W1[128 + t]; W1s[256 + t] = W1[256 + t];
                   b1s[t] = b1[t]; }
    __syncthreads();
    float acc[8];
#pragma unroll
    for (int m = 0; m < 8; ++m) acc[m] = 0.f;
    float Racc = 0.f;
    for (int node = blockIdx.x * 16 + (t >> 4); node < N; node += ZBLOCKS * 16) {
        int s = rpS[node], e = rpS[node + 1];
        float w = (sub == 0) ? relw[node] : 0.f;
        for (int j = s + sub; j < e; j += 16) w += relw[colS[j]];
#pragma unroll
        for (int off = 1; off < 16; off <<= 1) w += __shfl_xor(w, off);
        float4 gv = g1[node];
        float zw = w * gv.w;                       // z * dinv
#pragma unroll
        for (int m = 0; m < 8; ++m) {
            int c = sub * 8 + m;
            float h = fmaxf(gv.x * W1s[c] + gv.y * W1s[128 + c] + gv.z * W1s[256 + c] + b1s[c], 0.f);
            acc[m] += zw * h;
        }
        if (sub == 0) Racc += rel[node];
    }
#pragma unroll
    for (int m = 0; m < 8; ++m) {
        acc[m] += __shfl_xor(acc[m], 16);
        acc[m] += __shfl_xor(acc[m], 32);
    }
    Racc += __shfl_xor(Racc, 16);
    Racc += __shfl_xor(Racc, 32);
    if (lane < 16) {
#pragma unroll
        for (int m = 0; m < 8; ++m) sS[wid][sub * 8 + m] = acc[m];
    }
    if (lane == 0) sS[wid][128] = Racc;
    __syncthreads();
    if (t < 129) part[blockIdx.x * 132 + t] = sS[0][t] + sS[1][t] + sS[2][t] + sS[3][t];
}

// ---------------- reduce part columns in parallel (129 blocks) ----------------
__global__ void k_reduce_part(const float* __restrict__ part, int nblocks, float* __restrict__ small) {
    int c = blockIdx.x;   // 0..128 (128 == R -> small[260])
    float acc = 0.f;
    for (int b = threadIdx.x; b < nblocks; b += blockDim.x) acc += part[b * 132 + c];
    __shared__ float sd[256];
    sd[threadIdx.x] = acc; __syncthreads();
    for (int off = 128; off; off >>= 1) { if (threadIdx.x < off) sd[threadIdx.x] += sd[threadIdx.x + off]; __syncthreads(); }
    if (threadIdx.x == 0) small[132 + c] = sd[0];
}

// ---------------- parallel tail matvecs: 1024 threads, 8-way K slices ----------------
// t1 = S@W2 + R*b2;  newT = trainOT + t1@Wv + R*bv
__global__ void k_tinytail(const float* __restrict__ trainOT, const float* __restrict__ W2,
                           const float* __restrict__ b2, const float* __restrict__ Wv,
                           const float* __restrict__ bv, float* __restrict__ small,
                           float* __restrict__ out_tail) {
    __shared__ float partial[1024];
    __shared__ float Ss[128];
    __shared__ float t1[128];
    int t = threadIdx.x;           // 1024
    int o = t & 127, sl = t >> 7;  // 8 K-slices of 16
    if (t < 128) Ss[t] = small[132 + t];
    __syncthreads();
    float R = small[260];
    float acc = 0.f;
#pragma unroll
    for (int j = sl * 16; j < sl * 16 + 16; ++j) acc += Ss[j] * W2[j * 128 + o];
    partial[t] = acc; __syncthreads();
    if (t < 128) {
        float v = R * b2[t];
#pragma unroll
        for (int k = 0; k < 8; ++k) v += partial[t + 128 * k];
        t1[t] = v;
    }
    __syncthreads();
    float acc2 = 0.f;
#pragma unroll
    for (int j = sl * 16; j < sl * 16 + 16; ++j) acc2 += t1[j] * Wv[j * 128 + o];
    partial[t] = acc2; __syncthreads();
    if (t < 128) {
        float v = R * bv[t];
#pragma unroll
        for (int k = 0; k < 8; ++k) v += partial[t + 128 * k];
        float nt = trainOT[t] + v;
        small[264 + t] = nt;
        out_tail[t] = nt;
    }
}

// ---------------- speak: out[j] = newT @ Ws[:,j] + bs[j], 4 K-slices, LDS reduce ----------
__global__ void k_speak(const float* __restrict__ Ws, const float* __restrict__ bs,
                        const float* __restrict__ small, float* __restrict__ out, int out_n) {
    __shared__ float nt[128];
    __shared__ float s0[256], s1[256];
    int t = threadIdx.x;
    if (t < 128) nt[t] = small[264 + t];
    __syncthreads();
    int jj = (t & 63) * 2, sl = t >> 6;       // 4 K-slices of 32
    int j = blockIdx.x * 128 + jj;
    float a0 = 0.f, a1 = 0.f;
    if (j < out_n) {
        const float* w = Ws + (size_t)(sl * 32) * out_n + j;
        for (int k = 0; k < 32; ++k) {
            float cv = nt[sl * 32 + k];
            float2 r = *reinterpret_cast<const float2*>(w + (size_t)k * out_n);
            a0 += cv * r.x; a1 += cv * r.y;
        }
    }
    s0[t] = a0; s1[t] = a1; __syncthreads();
    if (t < 64 && j < out_n) {
        out[j]     = s0[t] + s0[t + 64] + s0[t + 128] + s0[t + 192] + bs[j];
        out[j + 1] = s1[t] + s1[t + 64] + s1[t + 128] + s1[t + 192] + bs[j + 1];
    }
}

extern "C" void kernel_launch(void* const* d_in, const int* in_sizes, int n_in,
                              void* d_out, int out_size, void* d_ws, size_t ws_size,
                              hipStream_t stream) {
    const float* features = (const float*)d_in[0];
    const int*   eidx     = (const int*)d_in[1];
    const float* trainOT  = (const float*)d_in[2];
    const float* W1 = (const float*)d_in[3];
    const float* b1 = (const float*)d_in[4];
    const float* W2 = (const float*)d_in[5];
    const float* b2 = (const float*)d_in[6];
    const float* Wq = (const float*)d_in[7];
    const float* bq = (const float*)d_in[8];
    const float* Wk = (const float*)d_in[9];
    const float* bk = (const float*)d_in[10];
    const float* Wv = (const float*)d_in[11];
    const float* bv = (const float*)d_in[12];
    const float* Ws = (const float*)d_in[13];
    const float* bs = (const float*)d_in[14];

    int N = in_sizes[0] / 3;
    int E = in_sizes[1] / 2;
    int NB = (N + 255) >> 8;
    int CS = (E + NCHUNK - 1) / NCHUNK;

    char* ws = (char*)d_ws;
    int*   rpD   = (int*)(ws + O_RPD);
    int*   rpS   = (int*)(ws + O_RPS);
    float* dinv  = (float*)(ws + O_DINV);
    float* small = (float*)(ws + O_SMALL);
    float* y     = (float*)(ws + O_Y);
    float* relw  = (float*)(ws + O_RELW);
    float* rel   = (float*)(ws + O_REL);
    int*   ghD   = (int*)(ws + O_GHD);
    int*   ghS   = (int*)(ws + O_GHS);
    int*   goD   = (int*)(ws + O_GOD);
    int*   goS   = (int*)(ws + O_GOS);
    int*   bsD   = (int*)(ws + O_BSD);
    int*   bsS   = (int*)(ws + O_BSS);
    float* part  = (float*)(ws + O_PART);
    float4* xs4  = (float4*)(ws + O_XS);
    float4* g1   = (float4*)(ws + O_G1);
    unsigned int* srtD = (unsigned int*)(ws + O_SRTD);
    unsigned int* srtS = (unsigned int*)(ws + O_SRTS);
    int*   colD  = (int*)(ws + O_COLD);
    int*   colS  = (int*)(ws + O_COLS);
    float* out   = (float*)d_out;
    int out_n = out_size - 128;

    k_hist<<<dim3(NCHUNK + 1, 2), 256, 0, stream>>>(eidx, ghD, ghS,
                                                    trainOT, Wq, bq, Wk, bk, W2, b2, small,
                                                    E, CS, NB);
    k_bstart<<<1, 256, 0, stream>>>(ghD, ghS, bsD, bsS, NB);
    k_goff<<<dim3(NB, 2), 256, 0, stream>>>(ghD, ghS, bsD, bsS, goD, goS, NB);
    k_scatter<<<dim3(NCHUNK, 2), 256, 0, stream>>>(eidx, goD, goS, srtD, srtS, E, CS, NB);
    k_build<<<dim3(NB, 2), 256, 0, stream>>>(srtD, srtS, bsD, bsS, rpD, rpS, colD, colS,
                                             dinv, features, xs4, N, NB);
    k_y<<<(N + 15) / 16, 256, 0, stream>>>(xs4, rpD, colD, dinv, W1, b1, small, g1, y, N);
    k_dv<<<(N + 15) / 16, 256, 0, stream>>>(y, rpD, colD, dinv, small, relw, rel, N);
    k_z<<<ZBLOCKS, 256, 0, stream>>>(g1, rpS, colS, relw, rel, W1, b1, part, N);
    k_reduce_part<<<129, 256, 0, stream>>>(part, ZBLOCKS, small);
    k_tinytail<<<1, 1024, 0, stream>>>(trainOT, W2, b2, Wv, bv, small, out + out_n);
    k_speak<<<(out_n + 127) / 128, 256, 0, stream>>>(Ws, bs, small, out, out_n);
}